// Round 7
// baseline (1146.337 us; speedup 1.0000x reference)
//
#include <hip/hip_runtime.h>

typedef unsigned short u16;
typedef unsigned int u32;
typedef unsigned long long u64;
typedef short s16x8 __attribute__((ext_vector_type(8)));
typedef float f32x4 __attribute__((ext_vector_type(4)));
typedef u32 u32x4 __attribute__((ext_vector_type(4)));

#define T_SEQ 40
#define EMB 300
#define KPAD 320
#define NCOL 3072   // 3H * 2 dirs
#define HS 262144   // 512*512 elems (one dir, one slot)

__device__ __forceinline__ u16 f2bf(float x) {
  u32 u = __builtin_bit_cast(u32, x);
  u32 r = (u + 0x7fffu + ((u >> 16) & 1u)) >> 16;  // RNE
  return (u16)r;
}
__device__ __forceinline__ float bf2f(u16 h) {
  return __builtin_bit_cast(float, ((u32)h) << 16);
}
#define LOG2E 1.4426950408889634f
__device__ __forceinline__ float sigm(float x) {
  return 1.0f / (1.0f + __builtin_amdgcn_exp2f(-x * LOG2E));
}
__device__ __forceinline__ float fast_tanh(float x) {
  return 1.0f - 2.0f / (1.0f + __builtin_amdgcn_exp2f(2.0f * LOG2E * x));
}

// ---- init: zero flag + claim counters (sc1-only state -> replay-safe), mask bitmaps
__global__ void k_init(const int* __restrict__ idxs, u64* __restrict__ mask,
                       int* __restrict__ bar) {
  int i = blockIdx.x * 256 + threadIdx.x;
  if (i < 264) __hip_atomic_store(&bar[i], 0, __ATOMIC_RELAXED, __HIP_MEMORY_SCOPE_AGENT);
  if (i < 512) {
    u64 b = 0;
    for (int t = 0; t < T_SEQ; ++t)
      if (idxs[i * T_SEQ + t] != 0) b |= (1ull << t);
    mask[i] = b;
  }
}

// ---- emb f32 [V][300] -> bf16 [V][320] (zero-padded), done once
__global__ void k_prep_emb(const float* __restrict__ emb, u16* __restrict__ emb16) {
  for (int idx = blockIdx.x * 256 + threadIdx.x; idx < 50000 * 160; idx += 4096 * 256) {
    int row = idx / 160, c2 = idx - row * 160;
    int c0 = 2 * c2;
    float v0 = (c0 < EMB) ? emb[(size_t)row * EMB + c0] : 0.0f;
    float v1 = (c0 + 1 < EMB) ? emb[(size_t)row * EMB + c0 + 1] : 0.0f;
    ((u32*)emb16)[(size_t)row * 160 + c2] = (u32)f2bf(v0) | ((u32)f2bf(v1) << 16);
  }
}

// ---- pack w_ih (both dirs) to bf16, K padded 300 -> 320
__global__ void k_prep_wih(const float* __restrict__ wf, const float* __restrict__ wb,
                           u16* __restrict__ wih) {
  int n = blockIdx.x, e = threadIdx.x;
  int dir = (n >= 1536);
  int g = n - dir * 1536;
  const float* src = dir ? wb : wf;
  float v = (e < EMB) ? src[(size_t)g * EMB + e] : 0.0f;
  wih[(size_t)n * KPAD + e] = f2bf(v);
}

// ---- split w_hh (both dirs) into bf16 hi/lo
__global__ void k_prep_whh(const float* __restrict__ wf, const float* __restrict__ wb,
                           u16* __restrict__ hi, u16* __restrict__ lo) {
  int n = blockIdx.x, k = threadIdx.x;
  int dir = (n >= 1536);
  int g = n - dir * 1536;
  float v = (dir ? wb : wf)[(size_t)g * 512 + k];
  u16 h = f2bf(v);
  hi[(size_t)n * 512 + k] = h;
  lo[(size_t)n * 512 + k] = f2bf(v - bf2f(h));
}

__global__ void k_prep_bias(const float* __restrict__ bihf, const float* __restrict__ bihb,
                            const float* __restrict__ bhhf, const float* __restrict__ bhhb,
                            float* __restrict__ bias_ih, float* __restrict__ bias_hh) {
  int i = blockIdx.x * 1024 + threadIdx.x;
  if (i >= 3072) return;
  int dir = (i >= 1536);
  int g = i - dir * 1536;
  bias_ih[i] = dir ? bihb[g] : bihf[g];
  bias_hh[i] = dir ? bhhb[g] : bhhf[g];
}

// ---- phase A: gi[tok][n] = emb16[idx[tok]] . wih[n] + b_ih[n], output bf16 (nt stores).
__global__ __launch_bounds__(256) void k_gi_gemm(
    const int* __restrict__ idxs, const float* __restrict__ emb,
    const u16* __restrict__ emb16, int use_emb16,
    const u16* __restrict__ wih, const float* __restrict__ bias_ih,
    u16* __restrict__ gi) {
  __shared__ __align__(16) char smem[34816];
  u16(*As)[40] = (u16(*)[40])smem;            // 10240 B
  u16(*Bs)[40] = (u16(*)[40])(smem + 10240);  // 10240 B
  u16(*Cs)[136] = (u16(*)[136])smem;          // 34816 B (reused after K loop)

  const int m0 = blockIdx.x * 128;
  const int n0 = blockIdx.y * 128;
  const int t = threadIdx.x;
  const int w = t >> 6, l = t & 63;
  const int wm = (w >> 1) * 64, wn = (w & 1) * 64;
  const int lr = l & 15, lg = l >> 4;

  f32x4 acc[4][4];
#pragma unroll
  for (int i = 0; i < 4; ++i)
#pragma unroll
    for (int j = 0; j < 4; ++j) acc[i][j] = (f32x4)0.0f;

  const int arow = t >> 1, aseg = t & 1;
  const int tok = idxs[m0 + arow];
  const float* aerow = emb + (size_t)tok * EMB;
  const u16* aerow16 = emb16 + (size_t)tok * KPAD;
  const u16* brow_p = wih + (size_t)(n0 + arow) * KPAD;

  for (int kc = 0; kc < 10; ++kc) {
    const int k0 = kc * 32;
    if (use_emb16) {
      *(uint4*)&As[arow][aseg * 16] = *(const uint4*)(aerow16 + k0 + aseg * 16);
      *(uint4*)(&As[arow][aseg * 16] + 8) = *(const uint4*)(aerow16 + k0 + aseg * 16 + 8);
    } else {
      int cb = k0 + aseg * 16;
      u16* d = &As[arow][aseg * 16];
      if (cb + 15 < EMB) {
        const float4* s = (const float4*)(aerow + cb);
        float4 v0 = s[0], v1 = s[1], v2 = s[2], v3 = s[3];
        uint4 w0, w1;
        w0.x = (u32)f2bf(v0.x) | ((u32)f2bf(v0.y) << 16);
        w0.y = (u32)f2bf(v0.z) | ((u32)f2bf(v0.w) << 16);
        w0.z = (u32)f2bf(v1.x) | ((u32)f2bf(v1.y) << 16);
        w0.w = (u32)f2bf(v1.z) | ((u32)f2bf(v1.w) << 16);
        w1.x = (u32)f2bf(v2.x) | ((u32)f2bf(v2.y) << 16);
        w1.y = (u32)f2bf(v2.z) | ((u32)f2bf(v2.w) << 16);
        w1.z = (u32)f2bf(v3.x) | ((u32)f2bf(v3.y) << 16);
        w1.w = (u32)f2bf(v3.z) | ((u32)f2bf(v3.w) << 16);
        *(uint4*)d = w0;
        *(uint4*)(d + 8) = w1;
      } else {
#pragma unroll
        for (int e = 0; e < 16; ++e) {
          int c = cb + e;
          d[e] = (c < EMB) ? f2bf(aerow[c]) : (u16)0;
        }
      }
    }
    {
      const u16* s = brow_p + k0 + aseg * 16;
      u16* d = &Bs[arow][aseg * 16];
      *(uint4*)d = *(const uint4*)s;
      *(uint4*)(d + 8) = *(const uint4*)(s + 8);
    }
    __syncthreads();
    s16x8 av[4], bv[4];
#pragma unroll
    for (int i = 0; i < 4; ++i) av[i] = *(const s16x8*)&As[wm + i * 16 + lr][lg * 8];
#pragma unroll
    for (int j = 0; j < 4; ++j) bv[j] = *(const s16x8*)&Bs[wn + j * 16 + lr][lg * 8];
#pragma unroll
    for (int i = 0; i < 4; ++i)
#pragma unroll
      for (int j = 0; j < 4; ++j)
        acc[i][j] = __builtin_amdgcn_mfma_f32_16x16x32_bf16(av[i], bv[j], acc[i][j], 0, 0, 0);
    __syncthreads();
  }

  float bj[4];
#pragma unroll
  for (int j = 0; j < 4; ++j) bj[j] = bias_ih[n0 + wn + j * 16 + lr];
#pragma unroll
  for (int i = 0; i < 4; ++i)
#pragma unroll
    for (int j = 0; j < 4; ++j)
#pragma unroll
      for (int r = 0; r < 4; ++r)
        Cs[wm + i * 16 + lg * 4 + r][wn + j * 16 + lr] = f2bf(acc[i][j][r] + bj[j]);
  __syncthreads();
#pragma unroll
  for (int rr = t >> 4; rr < 128; rr += 16) {
    const int cseg = (t & 15) * 8;
    __builtin_nontemporal_store(*(const u32x4*)&Cs[rr][cseg],
                                (u32x4*)(gi + (size_t)(m0 + rr) * NCOL + n0 + cseg));
  }
}

// ---- phase B: persistent bidirectional GRU, XCD-local groups, FINE-GRAINED flags.
// 256 blocks (1/CU via 96KB LDS), 512 threads. Block claims (XCD, slot) via XCC_ID.
// Slot q owns h cols [16q,16q+16); k-chunk kc gated on flags of slots 2kc,2kc+1 only
// (wave-ballot of one flag-line load). No __syncthreads / s_barrier in the steady
// state: per-wave vmcnt drain + LDS arrival counter -> one sc1 flag store per round.
// h: packed u32 hi|lo, plain L2 stores/loads (XCD-closed groups), 8-slot ring.
__global__ __launch_bounds__(512, 2) void k_gru_persist(
    const u16* __restrict__ whh_hi, const u16* __restrict__ whh_lo,
    const float* __restrict__ bias_hh, const u16* __restrict__ gi,
    const u64* __restrict__ mask, u32* __restrict__ hpk,
    float* __restrict__ ymax, int* __restrict__ bar) {
  extern __shared__ u16 wlds[];  // [64 kcg][48 col][8] hi at 0, lo at 24576 (u16 units)
  __shared__ int s_claim[2];
  __shared__ int s_arrive;
  const int t = threadIdx.x;
  if (t == 0) {
    int xcd;
    asm volatile("s_getreg_b32 %0, hwreg(HW_REG_XCC_ID)" : "=s"(xcd));
    xcd &= 7;
    int slot =
        __hip_atomic_fetch_add(&bar[256 + xcd], 1, __ATOMIC_RELAXED, __HIP_MEMORY_SCOPE_AGENT);
    s_claim[0] = xcd;
    s_claim[1] = slot & 31;
    s_arrive = 0;
  }
  __syncthreads();
  const int G = s_claim[0];   // group == physical XCD
  const int jt = s_claim[1];  // 0..31 within group (owns j cols [16jt,16jt+16))
  const int mt = G >> 1, dir = G & 1;
  const int m0 = mt * 128, j0 = jt * 16;
  const int wbase = dir * 1536;
  const int w = t >> 6, l = t & 63, lr = l & 15, lg = l >> 4;
  u32* flags = (u32*)bar + G * 32;  // one 128B line per group

  // stage w_hh hi/lo slice into LDS in fragment order
  for (int c = t; c < 3072; c += 512) {
    const int col = c % 48, kcg = c / 48;
    const int g = col >> 4, jj = col & 15;
    const int k = (kcg >> 2) * 32 + (kcg & 3) * 8;
    const size_t off = (size_t)(wbase + g * 512 + j0 + jj) * 512 + k;
    *(uint4*)&wlds[c * 8] = *(const uint4*)(whh_hi + off);
    *(uint4*)&wlds[24576 + c * 8] = *(const uint4*)(whh_lo + off);
  }
  const int j = j0 + lr;
  const float bR = bias_hh[wbase + j];
  const float bZ = bias_hh[wbase + 512 + j];
  const float bN = bias_hh[wbase + 1024 + j];
  u64 mk[4];
  float hprev[4], ym[4];
  int mrow[4];
#pragma unroll
  for (int r = 0; r < 4; ++r) {
    mrow[r] = m0 + w * 16 + lg * 4 + r;
    mk[r] = mask[mrow[r]];
    hprev[r] = 0.0f;
    ym[r] = -3.402823466e38f;
  }
  __syncthreads();  // weights staged, claim published, s_arrive=0

  // prefetch gi for step 0 (nontemporal: keep L2 for the h ring)
  u16 gr[4], gz[4], gn[4];
  {
    const int tok0 = dir ? (T_SEQ - 1) : 0;
#pragma unroll
    for (int r = 0; r < 4; ++r) {
      const size_t gb = ((size_t)mrow[r] * T_SEQ + tok0) * NCOL + wbase + j;
      gr[r] = __builtin_nontemporal_load(gi + gb);
      gz[r] = __builtin_nontemporal_load(gi + gb + 512);
      gn[r] = __builtin_nontemporal_load(gi + gb + 1024);
    }
  }

  const int flid = l & 31;  // lane p polls flag[p]
  const size_t abase = (size_t)(m0 + w * 16 + lr) * 512 + lg * 8;  // u32 elems

  for (int s = 0; s < T_SEQ; ++s) {
    const int tok = dir ? (T_SEQ - 1 - s) : s;
    f32x4 acc[3];
    acc[0] = acc[1] = acc[2] = (f32x4)0.0f;

    if (s > 0) {  // step 0: h=0 -> gh contribution is 0 (biases added in epilogue)
      const u32* hs = hpk + (size_t)((s & 7) * 2 + dir) * HS;
      u64 rdy = 0;
#pragma unroll
      for (int kc = 0; kc < 16; ++kc) {
        // gate: partners 2kc, 2kc+1 must have published h_s (flag >= s)
        while (((rdy >> (2 * kc)) & (rdy >> (2 * kc + 1)) & 1ull) == 0) {
          u32 f = __hip_atomic_load(&flags[flid], __ATOMIC_RELAXED, __HIP_MEMORY_SCOPE_AGENT);
          rdy = __ballot(f >= (u32)s);
          asm volatile("" ::: "memory");
        }
        const uint4* ap = (const uint4*)(hs + abase + kc * 32);
        uint4 q0 = ap[0], q1 = ap[1];
        u32 hw[8];
        *(uint4*)&hw[0] = q0;
        *(uint4*)&hw[4] = q1;
        u32 ahw[4], alw[4];
#pragma unroll
        for (int i = 0; i < 4; ++i) {
          ahw[i] = (hw[2 * i] & 0xFFFFu) | (hw[2 * i + 1] << 16);
          alw[i] = (hw[2 * i] >> 16) | (hw[2 * i + 1] & 0xFFFF0000u);
        }
        const s16x8 ah = __builtin_bit_cast(s16x8, *(uint4*)ahw);
        const s16x8 al = __builtin_bit_cast(s16x8, *(uint4*)alw);
        const int bbase = ((kc * 4 + lg) * 48 + lr) * 8;
#pragma unroll
        for (int g = 0; g < 3; ++g) {
          const s16x8 bh = *(const s16x8*)&wlds[bbase + g * 128];
          const s16x8 bl = *(const s16x8*)&wlds[24576 + bbase + g * 128];
          acc[g] = __builtin_amdgcn_mfma_f32_16x16x32_bf16(ah, bh, acc[g], 0, 0, 0);
          acc[g] = __builtin_amdgcn_mfma_f32_16x16x32_bf16(al, bh, acc[g], 0, 0, 0);
          acc[g] = __builtin_amdgcn_mfma_f32_16x16x32_bf16(ah, bl, acc[g], 0, 0, 0);
        }
      }
    }

    // epilogue: gates + h update (+ running masked max)
    u32 hpack[4];
#pragma unroll
    for (int r = 0; r < 4; ++r) {
      const float rg = sigm(bf2f(gr[r]) + acc[0][r] + bR);
      const float zg = sigm(bf2f(gz[r]) + acc[1][r] + bZ);
      const float ng = fast_tanh(bf2f(gn[r]) + rg * (acc[2][r] + bN));
      const float hn = (1.0f - zg) * ng + zg * hprev[r];
      hprev[r] = hn;
      const u16 hh = f2bf(hn);
      const u16 hl = f2bf(hn - bf2f(hh));
      hpack[r] = (u32)hh | ((u32)hl << 16);
      if ((mk[r] >> tok) & 1ull) ym[r] = fmaxf(ym[r], hn);
    }

    if (s < T_SEQ - 1) {
      u32* hd = hpk + (size_t)(((s + 1) & 7) * 2 + dir) * HS;
#pragma unroll
      for (int r = 0; r < 4; ++r) hd[(size_t)mrow[r] * 512 + j] = hpack[r];
      // per-wave drain of the 4 h stores, then arrive; NO block-wide barrier
      asm volatile("s_waitcnt vmcnt(0)" ::: "memory");
      if (l == 0) atomicAdd(&s_arrive, 1);
      // prefetch next step's gi (after drain: never sits on a flag/arrival wait)
      const int tok1 = dir ? (T_SEQ - 2 - s) : (s + 1);
#pragma unroll
      for (int r = 0; r < 4; ++r) {
        const size_t gb = ((size_t)mrow[r] * T_SEQ + tok1) * NCOL + wbase + j;
        gr[r] = __builtin_nontemporal_load(gi + gb);
        gz[r] = __builtin_nontemporal_load(gi + gb + 512);
        gn[r] = __builtin_nontemporal_load(gi + gb + 1024);
      }
      if (t == 0) {  // all 8 waves' stores drained -> publish h_{s+1}
        while (__hip_atomic_load(&s_arrive, __ATOMIC_RELAXED, __HIP_MEMORY_SCOPE_WORKGROUP) <
               8 * (s + 1)) {
        }
        __hip_atomic_store(&flags[jt], (u32)(s + 1), __ATOMIC_RELAXED,
                           __HIP_MEMORY_SCOPE_AGENT);
      }
    }
  }

#pragma unroll
  for (int r = 0; r < 4; ++r)
    ymax[(size_t)mrow[r] * 1024 + dir * 512 + j] = ym[r];
}

extern "C" void kernel_launch(void* const* d_in, const int* in_sizes, int n_in,
                              void* d_out, int out_size, void* d_ws, size_t ws_size,
                              hipStream_t stream) {
  const int* idxs = (const int*)d_in[0];
  const float* emb = (const float*)d_in[1];
  const float* wihf = (const float*)d_in[2];
  const float* whhf = (const float*)d_in[3];
  const float* bihf = (const float*)d_in[4];
  const float* bhhf = (const float*)d_in[5];
  const float* wihb = (const float*)d_in[6];
  const float* whhb = (const float*)d_in[7];
  const float* bihb = (const float*)d_in[8];
  const float* bhhb = (const float*)d_in[9];
  float* ymax = (float*)d_out;  // [512][1024] f32

  char* ws = (char*)d_ws;
  u16* whh_hi = (u16*)(ws + 0);             //  3,145,728
  u16* whh_lo = (u16*)(ws + 3145728);       //  3,145,728
  u16* wih = (u16*)(ws + 6291456);          //  1,966,080
  float* bias_ih = (float*)(ws + 8257536);  //     12,288
  float* bias_hh = (float*)(ws + 8269824);  //     12,288
  u64* mask = (u64*)(ws + 8282112);         //      4,096
  int* bar = (int*)(ws + 8286208);          //      4,096 (flags[0..255] + claim[256..263])
  // SHARED region: emb16 (32,000,000; live only through k_gi_gemm) overlaps
  // hpk (16,777,216; [slot=8][dir=2][512][512] u32, live only in k_gru_persist)
  u16* emb16 = (u16*)(ws + 8290304);
  u32* hpk = (u32*)(ws + 8290304);
  u16* gi = (u16*)(ws + 40290304);  // 125,829,120  bf16 [20480][3072]; ends 166,119,424
  const int use_emb16 = (ws_size >= 166119424ull) ? 1 : 0;

  k_init<<<2, 256, 0, stream>>>(idxs, mask, bar);
  if (use_emb16) k_prep_emb<<<4096, 256, 0, stream>>>(emb, emb16);
  k_prep_wih<<<3072, 320, 0, stream>>>(wihf, wihb, wih);
  k_prep_whh<<<3072, 512, 0, stream>>>(whhf, whhb, whh_hi, whh_lo);
  k_prep_bias<<<3, 1024, 0, stream>>>(bihf, bihb, bhhf, bhhb, bias_ih, bias_hh);
  k_gi_gemm<<<dim3(160, 24), 256, 0, stream>>>(idxs, emb, emb16, use_emb16, wih, bias_ih, gi);

  hipFuncSetAttribute((const void*)k_gru_persist,
                      hipFuncAttributeMaxDynamicSharedMemorySize, 98304);
  k_gru_persist<<<dim3(256), dim3(512), 98304, stream>>>(whh_hi, whh_lo, bias_hh, gi, mask,
                                                         hpk, ymax, bar);
}

// Round 8
// 797.915 us; speedup vs baseline: 1.4367x; 1.4367x over previous
//
#include <hip/hip_runtime.h>

typedef unsigned short u16;
typedef unsigned int u32;
typedef unsigned long long u64;
typedef short s16x8 __attribute__((ext_vector_type(8)));
typedef float f32x4 __attribute__((ext_vector_type(4)));
typedef u32 u32x4 __attribute__((ext_vector_type(4)));

#define T_SEQ 40
#define EMB 300
#define KPAD 320
#define NCOL 3072  // 3H * 2 dirs

__device__ __forceinline__ u16 f2bf(float x) {
  u32 u = __builtin_bit_cast(u32, x);
  u32 r = (u + 0x7fffu + ((u >> 16) & 1u)) >> 16;  // RNE
  return (u16)r;
}
__device__ __forceinline__ float bf2f(u16 h) {
  return __builtin_bit_cast(float, ((u32)h) << 16);
}
#define LOG2E 1.4426950408889634f
__device__ __forceinline__ float sigm(float x) {
  return 1.0f / (1.0f + __builtin_amdgcn_exp2f(-x * LOG2E));
}
__device__ __forceinline__ float fast_tanh(float x) {
  return 1.0f - 2.0f / (1.0f + __builtin_amdgcn_exp2f(2.0f * LOG2E * x));
}

// ---- init: zero flag + claim counters, build per-row mask bitmaps
__global__ void k_init(const int* __restrict__ idxs, u64* __restrict__ mask,
                       int* __restrict__ bar) {
  int i = blockIdx.x * 256 + threadIdx.x;
  if (i < 264) __hip_atomic_store(&bar[i], 0, __ATOMIC_RELAXED, __HIP_MEMORY_SCOPE_AGENT);
  if (i < 512) {
    u64 b = 0;
    for (int t = 0; t < T_SEQ; ++t)
      if (idxs[i * T_SEQ + t] != 0) b |= (1ull << t);
    mask[i] = b;
  }
}

// ---- emb f32 [V][300] -> bf16 [V][320] (zero-padded), done once
__global__ void k_prep_emb(const float* __restrict__ emb, u16* __restrict__ emb16) {
  for (int idx = blockIdx.x * 256 + threadIdx.x; idx < 50000 * 160; idx += 4096 * 256) {
    int row = idx / 160, c2 = idx - row * 160;
    int c0 = 2 * c2;
    float v0 = (c0 < EMB) ? emb[(size_t)row * EMB + c0] : 0.0f;
    float v1 = (c0 + 1 < EMB) ? emb[(size_t)row * EMB + c0 + 1] : 0.0f;
    ((u32*)emb16)[(size_t)row * 160 + c2] = (u32)f2bf(v0) | ((u32)f2bf(v1) << 16);
  }
}

// ---- pack w_ih (both dirs) to bf16, K padded 300 -> 320
__global__ void k_prep_wih(const float* __restrict__ wf, const float* __restrict__ wb,
                           u16* __restrict__ wih) {
  int n = blockIdx.x, e = threadIdx.x;
  int dir = (n >= 1536);
  int g = n - dir * 1536;
  const float* src = dir ? wb : wf;
  float v = (e < EMB) ? src[(size_t)g * EMB + e] : 0.0f;
  wih[(size_t)n * KPAD + e] = f2bf(v);
}

// ---- w_hh (both dirs) -> single bf16 (RNE)
__global__ void k_prep_whh(const float* __restrict__ wf, const float* __restrict__ wb,
                           u16* __restrict__ w16) {
  int n = blockIdx.x, k = threadIdx.x;
  int dir = (n >= 1536);
  int g = n - dir * 1536;
  float v = (dir ? wb : wf)[(size_t)g * 512 + k];
  w16[(size_t)n * 512 + k] = f2bf(v);
}

__global__ void k_prep_bias(const float* __restrict__ bihf, const float* __restrict__ bihb,
                            const float* __restrict__ bhhf, const float* __restrict__ bhhb,
                            float* __restrict__ bias_ih, float* __restrict__ bias_hh) {
  int i = blockIdx.x * 1024 + threadIdx.x;
  if (i >= 3072) return;
  int dir = (i >= 1536);
  int g = i - dir * 1536;
  bias_ih[i] = dir ? bihb[g] : bihf[g];
  bias_hh[i] = dir ? bhhb[g] : bhhf[g];
}

// ---- phase A: gi[tok][n] = emb16[idx[tok]] . wih[n] + b_ih[n], output bf16 (nt stores).
__global__ __launch_bounds__(256) void k_gi_gemm(
    const int* __restrict__ idxs, const float* __restrict__ emb,
    const u16* __restrict__ emb16, int use_emb16,
    const u16* __restrict__ wih, const float* __restrict__ bias_ih,
    u16* __restrict__ gi) {
  __shared__ __align__(16) char smem[34816];
  u16(*As)[40] = (u16(*)[40])smem;            // 10240 B
  u16(*Bs)[40] = (u16(*)[40])(smem + 10240);  // 10240 B
  u16(*Cs)[136] = (u16(*)[136])smem;          // 34816 B (reused after K loop)

  const int m0 = blockIdx.x * 128;
  const int n0 = blockIdx.y * 128;
  const int t = threadIdx.x;
  const int w = t >> 6, l = t & 63;
  const int wm = (w >> 1) * 64, wn = (w & 1) * 64;
  const int lr = l & 15, lg = l >> 4;

  f32x4 acc[4][4];
#pragma unroll
  for (int i = 0; i < 4; ++i)
#pragma unroll
    for (int j = 0; j < 4; ++j) acc[i][j] = (f32x4)0.0f;

  const int arow = t >> 1, aseg = t & 1;
  const int tok = idxs[m0 + arow];
  const float* aerow = emb + (size_t)tok * EMB;
  const u16* aerow16 = emb16 + (size_t)tok * KPAD;
  const u16* brow_p = wih + (size_t)(n0 + arow) * KPAD;

  for (int kc = 0; kc < 10; ++kc) {
    const int k0 = kc * 32;
    if (use_emb16) {
      *(uint4*)&As[arow][aseg * 16] = *(const uint4*)(aerow16 + k0 + aseg * 16);
      *(uint4*)(&As[arow][aseg * 16] + 8) = *(const uint4*)(aerow16 + k0 + aseg * 16 + 8);
    } else {
      int cb = k0 + aseg * 16;
      u16* d = &As[arow][aseg * 16];
      if (cb + 15 < EMB) {
        const float4* s = (const float4*)(aerow + cb);
        float4 v0 = s[0], v1 = s[1], v2 = s[2], v3 = s[3];
        uint4 w0, w1;
        w0.x = (u32)f2bf(v0.x) | ((u32)f2bf(v0.y) << 16);
        w0.y = (u32)f2bf(v0.z) | ((u32)f2bf(v0.w) << 16);
        w0.z = (u32)f2bf(v1.x) | ((u32)f2bf(v1.y) << 16);
        w0.w = (u32)f2bf(v1.z) | ((u32)f2bf(v1.w) << 16);
        w1.x = (u32)f2bf(v2.x) | ((u32)f2bf(v2.y) << 16);
        w1.y = (u32)f2bf(v2.z) | ((u32)f2bf(v2.w) << 16);
        w1.z = (u32)f2bf(v3.x) | ((u32)f2bf(v3.y) << 16);
        w1.w = (u32)f2bf(v3.z) | ((u32)f2bf(v3.w) << 16);
        *(uint4*)d = w0;
        *(uint4*)(d + 8) = w1;
      } else {
#pragma unroll
        for (int e = 0; e < 16; ++e) {
          int c = cb + e;
          d[e] = (c < EMB) ? f2bf(aerow[c]) : (u16)0;
        }
      }
    }
    {
      const u16* s = brow_p + k0 + aseg * 16;
      u16* d = &Bs[arow][aseg * 16];
      *(uint4*)d = *(const uint4*)s;
      *(uint4*)(d + 8) = *(const uint4*)(s + 8);
    }
    __syncthreads();
    s16x8 av[4], bv[4];
#pragma unroll
    for (int i = 0; i < 4; ++i) av[i] = *(const s16x8*)&As[wm + i * 16 + lr][lg * 8];
#pragma unroll
    for (int j = 0; j < 4; ++j) bv[j] = *(const s16x8*)&Bs[wn + j * 16 + lr][lg * 8];
#pragma unroll
    for (int i = 0; i < 4; ++i)
#pragma unroll
      for (int j = 0; j < 4; ++j)
        acc[i][j] = __builtin_amdgcn_mfma_f32_16x16x32_bf16(av[i], bv[j], acc[i][j], 0, 0, 0);
    __syncthreads();
  }

  float bj[4];
#pragma unroll
  for (int j = 0; j < 4; ++j) bj[j] = bias_ih[n0 + wn + j * 16 + lr];
#pragma unroll
  for (int i = 0; i < 4; ++i)
#pragma unroll
    for (int j = 0; j < 4; ++j)
#pragma unroll
      for (int r = 0; r < 4; ++r)
        Cs[wm + i * 16 + lg * 4 + r][wn + j * 16 + lr] = f2bf(acc[i][j][r] + bj[j]);
  __syncthreads();
#pragma unroll
  for (int rr = t >> 4; rr < 128; rr += 16) {
    const int cseg = (t & 15) * 8;
    __builtin_nontemporal_store(*(const u32x4*)&Cs[rr][cseg],
                                (u32x4*)(gi + (size_t)(m0 + rr) * NCOL + n0 + cseg));
  }
}

// ---- phase B: persistent bidirectional GRU. 16 groups of 16 blocks; group =
// (m-tile 64, dir), XCD-local via XCC_ID claim (mt = xcd, dir = slot&1, jt = slot>>1).
// Block: 64 m x 32 j x 3 gates; w_hh single-bf16 slice (96KB) in LDS for all steps;
// h split hi/lo packed u32 (2 MFMA per gate per kc). Monolithic per-step barrier:
// per-wave vmcnt drain -> LDS arrive -> last wave publishes block flag (agent sc1);
// all waves poll all 16 group flags (1 lane each + __all). After the poll, h-loads
// stream unimpeded (no per-chunk gates). h ring (8 slots, 2MB/XCD) is L2-resident.
__global__ __launch_bounds__(512) void k_gru_persist(
    const u16* __restrict__ whh16, const float* __restrict__ bias_hh,
    const u16* __restrict__ gi, const u64* __restrict__ mask, u32* __restrict__ hpk,
    float* __restrict__ ymax, int* __restrict__ bar) {
  extern __shared__ u16 wlds[];  // [64 kcg][96 col][8] u16 = 96 KB
  __shared__ int s_claim[2];
  __shared__ int s_arrive;
  const int t = threadIdx.x;
  if (t == 0) {
    int xcd;
    asm volatile("s_getreg_b32 %0, hwreg(HW_REG_XCC_ID)" : "=s"(xcd));
    xcd &= 7;
    int slot =
        __hip_atomic_fetch_add(&bar[256 + xcd], 1, __ATOMIC_RELAXED, __HIP_MEMORY_SCOPE_AGENT);
    s_claim[0] = xcd;
    s_claim[1] = slot & 31;
    s_arrive = 0;
  }
  __syncthreads();
  const int mt = s_claim[0];    // m-tile == physical XCD
  const int slot = s_claim[1];  // 0..31 within XCD
  const int dir = slot & 1;
  const int jt = slot >> 1;  // 0..15: owns j cols [32jt, 32jt+32)
  const int m0 = mt * 64, j0 = jt * 32;
  const int wbase = dir * 1536;
  const int w = t >> 6, l = t & 63, lr = l & 15, lg = l >> 4;
  const int mh = w >> 1, jh = w & 1;  // wave tile: (16 m) x (16 j), 4x2 waves

  // stage w_hh bf16 slice into LDS in fragment order: [kcg=kc*4+lg][col=g*32+jj][8]
  for (int c = t; c < 6144; c += 512) {
    const int col = c % 96, kcg = c / 96;
    const int g = col >> 5, jj = col & 31;
    const int k = (kcg >> 2) * 32 + (kcg & 3) * 8;
    const size_t off = (size_t)(wbase + g * 512 + j0 + jj) * 512 + k;
    *(uint4*)&wlds[c * 8] = *(const uint4*)(whh16 + off);
  }
  const int jg = j0 + jh * 16 + lr;  // this lane's hidden col (0..511)
  const float bR = bias_hh[wbase + jg];
  const float bZ = bias_hh[wbase + 512 + jg];
  const float bN = bias_hh[wbase + 1024 + jg];
  u64 mk[4];
  float hprev[4], ym[4];
  int mrow[4];
#pragma unroll
  for (int r = 0; r < 4; ++r) {
    mrow[r] = m0 + mh * 16 + lg * 4 + r;  // global batch row (C/D frag: row=lg*4+r)
    mk[r] = mask[mrow[r]];
    hprev[r] = 0.0f;
    ym[r] = -3.402823466e38f;
  }
  __syncthreads();  // weights staged, claim published

  const int pollidx = mt * 32 + 2 * (l & 15) + dir;  // lane polls one group flag
  const size_t aoff = (size_t)(mh * 16 + lr) * 512;  // A-frag row base (u32 elems)

  for (int s = 0; s < T_SEQ; ++s) {
    const int tok = dir ? (T_SEQ - 1 - s) : s;

    if (s > 0) {  // wait: all 16 blocks of this group published h_s
      const u32 tgt = (u32)s;
      while (true) {
        u32 f = __hip_atomic_load((u32*)&bar[pollidx], __ATOMIC_RELAXED,
                                  __HIP_MEMORY_SCOPE_AGENT);
        if (__all(f >= tgt)) break;
        __builtin_amdgcn_s_sleep(1);
      }
    }

    // prefetch gi for this step (latency hides under the K loop)
    u16 gr[4], gz[4], gn[4];
#pragma unroll
    for (int r = 0; r < 4; ++r) {
      const size_t gb = ((size_t)mrow[r] * T_SEQ + tok) * NCOL + wbase + jg;
      gr[r] = __builtin_nontemporal_load(gi + gb);
      gz[r] = __builtin_nontemporal_load(gi + gb + 512);
      gn[r] = __builtin_nontemporal_load(gi + gb + 1024);
    }

    f32x4 acc[3];
    acc[0] = acc[1] = acc[2] = (f32x4)0.0f;
    if (s > 0) {  // step 0: h=0 -> gh contribution is 0
      const u32* hs = hpk + ((((size_t)(s & 7)) * 2 + dir) * 8 + mt) * 32768;
#pragma unroll
      for (int kc = 0; kc < 16; ++kc) {
        const uint4* ap = (const uint4*)(hs + aoff + kc * 32 + lg * 8);
        uint4 q0 = ap[0], q1 = ap[1];
        u32 hw[8];
        *(uint4*)&hw[0] = q0;
        *(uint4*)&hw[4] = q1;
        u32 ahw[4], alw[4];
#pragma unroll
        for (int i = 0; i < 4; ++i) {
          ahw[i] = (hw[2 * i] & 0xFFFFu) | (hw[2 * i + 1] << 16);
          alw[i] = (hw[2 * i] >> 16) | (hw[2 * i + 1] & 0xFFFF0000u);
        }
        const s16x8 ah = __builtin_bit_cast(s16x8, *(uint4*)ahw);
        const s16x8 al = __builtin_bit_cast(s16x8, *(uint4*)alw);
        const int bb = ((kc * 4 + lg) * 96 + jh * 16 + lr) * 8;
#pragma unroll
        for (int g = 0; g < 3; ++g) {
          const s16x8 bh = *(const s16x8*)&wlds[bb + g * 256];
          acc[g] = __builtin_amdgcn_mfma_f32_16x16x32_bf16(ah, bh, acc[g], 0, 0, 0);
          acc[g] = __builtin_amdgcn_mfma_f32_16x16x32_bf16(al, bh, acc[g], 0, 0, 0);
        }
      }
    }

    // epilogue: gates + h update + running masked max
    u32 hpack[4];
#pragma unroll
    for (int r = 0; r < 4; ++r) {
      const float rg = sigm(bf2f(gr[r]) + acc[0][r] + bR);
      const float zg = sigm(bf2f(gz[r]) + acc[1][r] + bZ);
      const float ng = fast_tanh(bf2f(gn[r]) + rg * (acc[2][r] + bN));
      const float hn = (1.0f - zg) * ng + zg * hprev[r];
      hprev[r] = hn;
      const u16 hh = f2bf(hn);
      const u16 hl = f2bf(hn - bf2f(hh));
      hpack[r] = (u32)hh | ((u32)hl << 16);
      if ((mk[r] >> tok) & 1ull) ym[r] = fmaxf(ym[r], hn);
    }

    if (s < T_SEQ - 1) {
      u32* hd = hpk + ((((size_t)((s + 1) & 7)) * 2 + dir) * 8 + mt) * 32768;
#pragma unroll
      for (int r = 0; r < 4; ++r)
        hd[(size_t)(mh * 16 + lg * 4 + r) * 512 + jg] = hpack[r];
      asm volatile("s_waitcnt vmcnt(0)" ::: "memory");  // own stores at L2
      if (l == 0) {
        int old = atomicAdd(&s_arrive, 1);
        if (old == 8 * (s + 1) - 1)  // last wave of block -> publish h_{s+1}
          __hip_atomic_store((u32*)&bar[mt * 32 + slot], (u32)(s + 1), __ATOMIC_RELAXED,
                             __HIP_MEMORY_SCOPE_AGENT);
      }
    }
  }

#pragma unroll
  for (int r = 0; r < 4; ++r)
    ymax[(size_t)mrow[r] * 1024 + dir * 512 + jg] = ym[r];
}

extern "C" void kernel_launch(void* const* d_in, const int* in_sizes, int n_in,
                              void* d_out, int out_size, void* d_ws, size_t ws_size,
                              hipStream_t stream) {
  const int* idxs = (const int*)d_in[0];
  const float* emb = (const float*)d_in[1];
  const float* wihf = (const float*)d_in[2];
  const float* whhf = (const float*)d_in[3];
  const float* bihf = (const float*)d_in[4];
  const float* bhhf = (const float*)d_in[5];
  const float* wihb = (const float*)d_in[6];
  const float* whhb = (const float*)d_in[7];
  const float* bihb = (const float*)d_in[8];
  const float* bhhb = (const float*)d_in[9];
  float* ymax = (float*)d_out;  // [512][1024] f32

  char* ws = (char*)d_ws;
  u16* whh16 = (u16*)(ws + 0);              //  3,145,728  bf16 [3072][512]
  u16* wih = (u16*)(ws + 6291456);          //  1,966,080
  float* bias_ih = (float*)(ws + 8257536);  //     12,288
  float* bias_hh = (float*)(ws + 8269824);  //     12,288
  u64* mask = (u64*)(ws + 8282112);         //      4,096
  int* bar = (int*)(ws + 8286208);          //      4,096 (flags[0..255] + claim[256..263])
  // SHARED region: emb16 (32,000,000; live only through k_gi_gemm) overlaps
  // hpk (16,777,216; [slot=8][dir=2][mt=8][64][512] u32, live only in k_gru_persist)
  u16* emb16 = (u16*)(ws + 8290304);
  u32* hpk = (u32*)(ws + 8290304);
  u16* gi = (u16*)(ws + 40290304);  // 125,829,120  bf16 [20480][3072]; ends 166,119,424
  const int use_emb16 = (ws_size >= 166119424ull) ? 1 : 0;

  k_init<<<2, 256, 0, stream>>>(idxs, mask, bar);
  if (use_emb16) k_prep_emb<<<4096, 256, 0, stream>>>(emb, emb16);
  k_prep_wih<<<3072, 320, 0, stream>>>(wihf, wihb, wih);
  k_prep_whh<<<3072, 512, 0, stream>>>(whhf, whhb, whh16);
  k_prep_bias<<<3, 1024, 0, stream>>>(bihf, bihb, bhhf, bhhb, bias_ih, bias_hh);
  k_gi_gemm<<<dim3(160, 24), 256, 0, stream>>>(idxs, emb, emb16, use_emb16, wih, bias_ih, gi);

  hipFuncSetAttribute((const void*)k_gru_persist,
                      hipFuncAttributeMaxDynamicSharedMemorySize, 98304);
  k_gru_persist<<<dim3(256), dim3(512), 98304, stream>>>(whh16, bias_hh, gi, mask, hpk,
                                                         ymax, bar);
}